// Round 5
// baseline (275.205 us; speedup 1.0000x reference)
//
#include <hip/hip_runtime.h>
#include <stdint.h>

// ---------------- problem constants ----------------
#define NB   8      // batch
#define SS   2048   // seq
#define DD   1024   // embd
#define BOT  400    // bottleneck
#define BOTP 512    // padded bottleneck (padded weights zeroed -> h pad = relu(0) = 0)
#define NAD  25     // adapters
#define LN_EPS 1e-5f
#define NCH  128    // stats chunks per batch

typedef __attribute__((ext_vector_type(8))) short bf8_t;  // 8 bf16 (4 VGPRs)
typedef __attribute__((ext_vector_type(4))) float fx4;

__device__ __forceinline__ unsigned short f2bf(float f) {
  unsigned int u = __float_as_uint(f);
  u = (u + 0x7FFFu + ((u >> 16) & 1u)) >> 16;   // RNE bf16
  return (unsigned short)u;
}
// packed f32x2 -> bf16x2 (RNE), single instruction
__device__ __forceinline__ uint32_t cvtpk(float lo, float hi) {
  uint32_t r;
  asm("v_cvt_pk_bf16_f32 %0, %1, %2" : "=v"(r) : "v"(lo), "v"(hi));
  return r;
}

__device__ __forceinline__ void gload16(void* lds, const void* g) {
  __builtin_amdgcn_global_load_lds(
      (const __attribute__((address_space(1))) void*)(uintptr_t)g,
      (__attribute__((address_space(3))) void*)(uint32_t)(uintptr_t)lds,
      16, 0, 0);
}

// ---------------- kernel 1: fused weight-mix (high-ILP) + LN partial stats ----------------
// blocks [0,400)    : W_down dense mix (valid region contiguous: 400*1024 f32/adapter)
// blocks [400,800)  : W_up   dense mix (valid region contiguous: 1024*400 f32/adapter)
// blocks [800,808)  : wln/bln mix
// blocks [808,864)  : zero Wd pad rows 400..511
// blocks [864,920)  : zero Wu pad cols 400..511
// blocks [920,1944) : LN partial sums (8 batches x 128 chunks)
__global__ __launch_bounds__(256) void mixstats_kernel(
    const float* __restrict__ alphas,
    const float* __restrict__ WdAll, const float* __restrict__ WuAll,
    const float* __restrict__ wlnAll, const float* __restrict__ blnAll,
    const float* __restrict__ x,
    unsigned short* __restrict__ Wd, unsigned short* __restrict__ Wu,
    float* __restrict__ wln, float* __restrict__ bln,
    float* __restrict__ partials)
{
  const int tid = threadIdx.x;
  const int bid = blockIdx.x;

  if (bid >= 920) {                      // ---- stats ----
    const int g = bid - 920;
    const int b = g >> 7, c = g & 127;
    const float4* xb = (const float4*)(x + (size_t)b * SS * DD) + (size_t)c * 4096;
    float s = 0.f, q = 0.f;
#pragma unroll 4
    for (int i = tid; i < 4096; i += 256) {
      float4 v = xb[i];
      s += v.x + v.y + v.z + v.w;
      q += v.x * v.x + v.y * v.y + v.z * v.z + v.w * v.w;
    }
#pragma unroll
    for (int off = 32; off > 0; off >>= 1) { s += __shfl_down(s, off); q += __shfl_down(q, off); }
    __shared__ float red[8];
    const int wave = tid >> 6, lane = tid & 63;
    if (!lane) { red[wave] = s; red[wave + 4] = q; }
    __syncthreads();
    if (!tid) {
      partials[(b * NCH + c) * 2]     = red[0] + red[1] + red[2] + red[3];
      partials[(b * NCH + c) * 2 + 1] = red[4] + red[5] + red[6] + red[7];
    }
    return;
  }

  __shared__ float a[NAD];
  if (tid < NAD) a[tid] = alphas[tid];
  __syncthreads();

  if (bid < 800) {                       // ---- dense mixes: 25 loads in flight ----
    const int g = (bid < 400 ? bid : bid - 400) * 256 + tid;   // float4-group 0..102399
    const float4* src = (const float4*)(bid < 400 ? WdAll : WuAll) + g;
    float4 vals[NAD];
#pragma unroll
    for (int n = 0; n < NAD; ++n) vals[n] = src[(size_t)n * 102400];
    float4 acc = {0.f, 0.f, 0.f, 0.f};
#pragma unroll
    for (int n = 0; n < NAD; ++n) {
      acc.x += a[n] * vals[n].x; acc.y += a[n] * vals[n].y;
      acc.z += a[n] * vals[n].z; acc.w += a[n] * vals[n].w;
    }
    uint2 pk = { cvtpk(acc.x, acc.y), cvtpk(acc.z, acc.w) };
    if (bid < 400) {
      *(uint2*)(Wd + (size_t)g * 4) = pk;                    // Wd [512][1024] dense region
    } else {
      const int d = g / 100, bg = g - d * 100;               // Wu [1024][512]
      *(uint2*)(Wu + (size_t)d * BOTP + bg * 4) = pk;
    }
  } else if (bid < 808) {                // ---- wln / bln ----
    const int i = (bid - 800) * 256 + tid;
    const float* src = (i < DD) ? wlnAll : blnAll;
    const int j = (i < DD) ? i : (i - DD);
    float v[NAD];
#pragma unroll
    for (int n = 0; n < NAD; ++n) v[n] = src[(size_t)n * DD + j];
    float s = 0.f;
#pragma unroll
    for (int n = 0; n < NAD; ++n) s += a[n] * v[n];
    if (i < DD) wln[j] = s; else bln[j] = s;
  } else if (bid < 864) {                // ---- zero Wd rows 400..511 ----
    const int t = (bid - 808) * 256 + tid;
    int4 z = {0, 0, 0, 0};
    *(int4*)(Wd + 400 * 1024 + (size_t)t * 8) = z;
  } else {                               // ---- zero Wu cols 400..511 ----
    const int t = (bid - 864) * 256 + tid;
    const int row = t / 14, c8 = t - row * 14;
    int4 z = {0, 0, 0, 0};
    *(int4*)(Wu + (size_t)row * BOTP + 400 + c8 * 8) = z;
  }
}

// ---------------- kernel 2: GEMM1 with fused normalize ----------------
// H[16384][512] = relu( (x*s1+s2)[16384][1024] @ Wd[512][1024]^T ), bf16 out.
// R1-proven skeleton: single-buffered LDS, linear layout, stage->sync->compute->sync.
// A staged via registers (f32 loads prefetched 1 tile ahead; normalize+cvt_pk+ds_write_b128).
__global__ __launch_bounds__(256) void gemm1(
    const float* __restrict__ x, const unsigned short* __restrict__ Wdm,
    const float* __restrict__ partials, const float* __restrict__ wln,
    const float* __restrict__ bln, unsigned short* __restrict__ H)
{
  __shared__ char smraw[32768];
  unsigned short* As = (unsigned short*)smraw;             // [128][32] bf16, 8 KB
  unsigned short* Bs = (unsigned short*)(smraw + 8192);    // [128][32] bf16, 8 KB
  float* s1 = (float*)(smraw + 16384);                     // [1024] 4 KB
  float* s2 = (float*)(smraw + 20480);                     // [1024] 4 KB

  const int tid = threadIdx.x, wave = tid >> 6, lane = tid & 63;
  const int wr = wave >> 1, wc = wave & 1;
  const int bcol = blockIdx.x & 3, brow = blockIdx.x >> 2;
  const int b = brow >> 4;                                 // batch

  // LN coefficients: x_hat*wln+bln = x*s1 + s2
  double sd = 0.0, qd = 0.0;
#pragma unroll 8
  for (int i = 0; i < NCH; ++i) {
    sd += partials[(b * NCH + i) * 2];
    qd += partials[(b * NCH + i) * 2 + 1];
  }
  const float mu  = (float)(sd * (1.0 / 2097152.0));
  const float var = (float)(qd * (1.0 / 2097152.0)) - mu * mu;
  const float rs  = rsqrtf(var + LN_EPS);
  for (int c = tid; c < DD; c += 256) {
    const float v1 = rs * wln[c];
    s1[c] = v1; s2[c] = bln[c] - mu * v1;
  }

  const float* Ab = x + (size_t)(brow * 128) * DD;
  const unsigned short* Bb = Wdm + (size_t)(bcol * 128) * DD;
  const int row2 = tid >> 1;                 // 0..127 (one row per 2 threads)
  const int c16  = (tid & 1) * 16;           // half-row of BK=32

  auto loadA = [&](int k0, float4* xr) {
    const float* p = Ab + (size_t)row2 * DD + k0 + c16;
    xr[0] = *(const float4*)p;     xr[1] = *(const float4*)(p + 4);
    xr[2] = *(const float4*)(p + 8); xr[3] = *(const float4*)(p + 12);
  };
  auto writeA = [&](int k0, const float4* xr) {
    const float4 wA = *(const float4*)&s1[k0 + c16],      wB = *(const float4*)&s1[k0 + c16 + 4];
    const float4 wC = *(const float4*)&s1[k0 + c16 + 8],  wD = *(const float4*)&s1[k0 + c16 + 12];
    const float4 bA = *(const float4*)&s2[k0 + c16],      bB = *(const float4*)&s2[k0 + c16 + 4];
    const float4 bC = *(const float4*)&s2[k0 + c16 + 8],  bD = *(const float4*)&s2[k0 + c16 + 12];
    uint4 p0, p1;
    p0.x = cvtpk(xr[0].x * wA.x + bA.x, xr[0].y * wA.y + bA.y);
    p0.y = cvtpk(xr[0].z * wA.z + bA.z, xr[0].w * wA.w + bA.w);
    p0.z = cvtpk(xr[1].x * wB.x + bB.x, xr[1].y * wB.y + bB.y);
    p0.w = cvtpk(xr[1].z * wB.z + bB.z, xr[1].w * wB.w + bB.w);
    p1.x = cvtpk(xr[2].x * wC.x + bC.x, xr[2].y * wC.y + bC.y);
    p1.y = cvtpk(xr[2].z * wC.z + bC.z, xr[2].w * wC.w + bC.w);
    p1.z = cvtpk(xr[3].x * wD.x + bD.x, xr[3].y * wD.y + bD.y);
    p1.w = cvtpk(xr[3].z * wD.z + bD.z, xr[3].w * wD.w + bD.w);
    *(uint4*)&As[row2 * 32 + c16]     = p0;
    *(uint4*)&As[row2 * 32 + c16 + 8] = p1;
  };
  auto stageB = [&](int k0) {
#pragma unroll
    for (int i = 0; i < 2; ++i) {
      const int basee = (i * 256 + wave * 64) * 8;   // wave-uniform element base
      const int e   = basee + lane * 8;
      const int row = e >> 5, col = e & 31;
      gload16(&Bs[basee], Bb + (size_t)row * DD + k0 + col);
    }
  };

  fx4 acc[4][4] = {};
  auto compute = [&]() {
    bf8_t af[4], bf[4];
    const int hi8 = (lane >> 4) * 8;
#pragma unroll
    for (int m = 0; m < 4; ++m)
      af[m] = *(const bf8_t*)&As[(wr * 64 + m * 16 + (lane & 15)) * 32 + hi8];
#pragma unroll
    for (int n = 0; n < 4; ++n)
      bf[n] = *(const bf8_t*)&Bs[(wc * 64 + n * 16 + (lane & 15)) * 32 + hi8];
#pragma unroll
    for (int m = 0; m < 4; ++m)
#pragma unroll
      for (int n = 0; n < 4; ++n)
        acc[m][n] = __builtin_amdgcn_mfma_f32_16x16x32_bf16(af[m], bf[n], acc[m][n], 0, 0, 0);
  };

  float4 xrA[4], xrB[4];
  loadA(0, xrA); stageB(0); loadA(32, xrB);   // xrB prefetched deep ahead
  __syncthreads();                            // s1/s2 ready; Bs tile0 ready (vmcnt drained)
  writeA(0, xrA);
  __syncthreads();                            // As tile0 ready
#pragma unroll 1
  for (int t2 = 0; t2 < 16; ++t2) {
    {
      const int t = t2 * 2;
      compute();
      __syncthreads();                        // all reads of tile t done
      if (t < 31) {
        stageB((t + 1) * 32);
        writeA((t + 1) * 32, xrB);
        if (t + 2 < 32) loadA((t + 2) * 32, xrA);
      }
      __syncthreads();                        // tile t+1 ready
    }
    {
      const int t = t2 * 2 + 1;
      compute();
      __syncthreads();
      if (t < 31) {
        stageB((t + 1) * 32);
        writeA((t + 1) * 32, xrA);
        if (t + 2 < 32) loadA((t + 2) * 32, xrB);
      }
      __syncthreads();
    }
  }

  // epilogue: relu -> bf16 repack through LDS -> coalesced int4 stores
  unsigned short* Hs = (unsigned short*)smraw;   // [128][128] bf16, 32 KB
  const int r0l = wr * 64 + ((lane >> 4) << 2);
  const int c0l = wc * 64 + (lane & 15);
#pragma unroll
  for (int m = 0; m < 4; ++m)
#pragma unroll
    for (int n = 0; n < 4; ++n)
#pragma unroll
      for (int j = 0; j < 4; ++j) {
        float v = acc[m][n][j];
        Hs[(r0l + m * 16 + j) * 128 + (c0l + n * 16)] = f2bf(v > 0.f ? v : 0.f);
      }
  __syncthreads();
  const size_t outbase = (size_t)(brow * 128) * BOTP + (size_t)bcol * 128;
#pragma unroll
  for (int i = 0; i < 8; ++i) {
    const int idx = i * 256 + tid;
    const int row = idx >> 4, colg = idx & 15;
    *(int4*)(H + outbase + (size_t)row * BOTP + colg * 8) = *(const int4*)&Hs[row * 128 + colg * 8];
  }
}

// ---------------- kernel 3: GEMM2 + residual (R1-exact structure) ----------------
// out[16384][1024] = x + H[16384][512] @ Wu[1024][512]^T, f32 out.
__global__ __launch_bounds__(256) void gemm2(
    const unsigned short* __restrict__ A, const unsigned short* __restrict__ Bm,
    const float* __restrict__ Xres, float* __restrict__ out)
{
  __shared__ unsigned short As[128 * 32];
  __shared__ unsigned short Bs[128 * 32];
  const int tid = threadIdx.x, wave = tid >> 6, lane = tid & 63;
  const int wr = wave >> 1, wc = wave & 1;
  const int bcol = blockIdx.x & 7, brow = blockIdx.x >> 3;
  const unsigned short* Ab = A + (size_t)(brow * 128) * BOTP;
  const unsigned short* Bb = Bm + (size_t)(bcol * 128) * BOTP;

  fx4 acc[4][4] = {};
  for (int k0 = 0; k0 < 512; k0 += 32) {
#pragma unroll
    for (int i = 0; i < 2; ++i) {
      const int basee = (i * 256 + wave * 64) * 8;
      const int e   = basee + lane * 8;
      const int row = e >> 5, col = e & 31;
      gload16(&As[basee], Ab + (size_t)row * BOTP + k0 + col);
      gload16(&Bs[basee], Bb + (size_t)row * BOTP + k0 + col);
    }
    __syncthreads();
    bf8_t af[4], bf[4];
    const int hi8 = (lane >> 4) * 8;
#pragma unroll
    for (int m = 0; m < 4; ++m)
      af[m] = *(const bf8_t*)&As[(wr * 64 + m * 16 + (lane & 15)) * 32 + hi8];
#pragma unroll
    for (int n = 0; n < 4; ++n)
      bf[n] = *(const bf8_t*)&Bs[(wc * 64 + n * 16 + (lane & 15)) * 32 + hi8];
#pragma unroll
    for (int m = 0; m < 4; ++m)
#pragma unroll
      for (int n = 0; n < 4; ++n)
        acc[m][n] = __builtin_amdgcn_mfma_f32_16x16x32_bf16(af[m], bf[n], acc[m][n], 0, 0, 0);
    __syncthreads();
  }

  const int r0 = brow * 128 + wr * 64 + ((lane >> 4) << 2);
  const int c0 = bcol * 128 + wc * 64 + (lane & 15);
#pragma unroll
  for (int m = 0; m < 4; ++m)
#pragma unroll
    for (int n = 0; n < 4; ++n)
#pragma unroll
      for (int j = 0; j < 4; ++j) {
        const size_t off = (size_t)(r0 + m * 16 + j) * DD + (c0 + n * 16);
        out[off] = acc[m][n][j] + Xres[off];
      }
}

// ---------------- launcher ----------------
extern "C" void kernel_launch(void* const* d_in, const int* in_sizes, int n_in,
                              void* d_out, int out_size, void* d_ws, size_t ws_size,
                              hipStream_t stream)
{
  const float* x      = (const float*)d_in[0];
  const float* alphas = (const float*)d_in[1];
  const float* WdAll  = (const float*)d_in[2];
  const float* WuAll  = (const float*)d_in[3];
  const float* wlnAll = (const float*)d_in[6];
  const float* blnAll = (const float*)d_in[7];
  float* out = (float*)d_out;

  char* ws = (char*)d_ws;
  unsigned short* Wd  = (unsigned short*)ws;                  // [512][1024] bf16, 1 MB
  unsigned short* Wu  = (unsigned short*)(ws + (1u << 20));   // [1024][512] bf16, 1 MB
  float* wln          = (float*)(ws + (2u << 20));
  float* bln          = wln + DD;
  float* partials     = bln + DD;                             // 8*128*2 f32
  unsigned short* h   = (unsigned short*)(ws + (3u << 20));   // [16384][512] bf16, 16 MB

  mixstats_kernel<<<1944, 256, 0, stream>>>(alphas, WdAll, WuAll, wlnAll, blnAll, x,
                                            Wd, Wu, wln, bln, partials);
  gemm1<<<512, 256, 0, stream>>>(x, Wd, partials, wln, bln, h);
  gemm2<<<1024, 256, 0, stream>>>(h, Wu, x, out);
}

// Round 9
// 265.230 us; speedup vs baseline: 1.0376x; 1.0376x over previous
//
#include <hip/hip_runtime.h>
#include <stdint.h>

// ---------------- problem constants ----------------
#define NB   8      // batch
#define SS   2048   // seq
#define DD   1024   // embd
#define BOT  400    // bottleneck
#define BOTP 512    // padded bottleneck (padded weights zeroed -> h pad = relu(0) = 0)
#define NAD  25     // adapters
#define LN_EPS 1e-5f
#define NCH  128    // stats chunks per batch

typedef __attribute__((ext_vector_type(8))) short bf8_t;  // 8 bf16 (4 VGPRs)
typedef __attribute__((ext_vector_type(4))) float fx4;

__device__ __forceinline__ unsigned short f2bf(float f) {
  unsigned int u = __float_as_uint(f);
  u = (u + 0x7FFFu + ((u >> 16) & 1u)) >> 16;   // RNE bf16
  return (unsigned short)u;
}
// packed f32x2 -> bf16x2 (RNE), single instruction
__device__ __forceinline__ uint32_t cvtpk(float lo, float hi) {
  uint32_t r;
  asm("v_cvt_pk_bf16_f32 %0, %1, %2" : "=v"(r) : "v"(lo), "v"(hi));
  return r;
}

__device__ __forceinline__ void gload16(void* lds, const void* g) {
  __builtin_amdgcn_global_load_lds(
      (const __attribute__((address_space(1))) void*)(uintptr_t)g,
      (__attribute__((address_space(3))) void*)(uint32_t)(uintptr_t)lds,
      16, 0, 0);
}

// ---------------- kernel 1: fused weight-mix + LN partial stats (forced MLP) ----------------
// blocks [0,400)    : W_down dense mix
// blocks [400,800)  : W_up   dense mix
// blocks [800,808)  : wln/bln mix
// blocks [808,864)  : zero Wd pad rows 400..511
// blocks [864,920)  : zero Wu pad cols 400..511
// blocks [920,1944) : LN partial sums (8 batches x 128 chunks)
__global__ __launch_bounds__(256) void mixstats_kernel(
    const float* __restrict__ alphas,
    const float* __restrict__ WdAll, const float* __restrict__ WuAll,
    const float* __restrict__ wlnAll, const float* __restrict__ blnAll,
    const float* __restrict__ x,
    unsigned short* __restrict__ Wd, unsigned short* __restrict__ Wu,
    float* __restrict__ wln, float* __restrict__ bln,
    float* __restrict__ partials)
{
  const int tid = threadIdx.x;
  const int bid = blockIdx.x;

  if (bid >= 920) {                      // ---- stats: 16 loads in flight ----
    const int g = bid - 920;
    const int b = g >> 7, c = g & 127;
    const float4* xb = (const float4*)(x + (size_t)b * SS * DD) + (size_t)c * 4096;
    float4 v[16];
#pragma unroll
    for (int i = 0; i < 16; ++i) v[i] = xb[i * 256 + tid];
    __builtin_amdgcn_sched_barrier(0);   // all 16 loads issued before any use
    float s = 0.f, q = 0.f;
#pragma unroll
    for (int i = 0; i < 16; ++i) {
      s += v[i].x + v[i].y + v[i].z + v[i].w;
      q += v[i].x * v[i].x + v[i].y * v[i].y + v[i].z * v[i].z + v[i].w * v[i].w;
    }
#pragma unroll
    for (int off = 32; off > 0; off >>= 1) { s += __shfl_down(s, off); q += __shfl_down(q, off); }
    __shared__ float red[8];
    const int wave = tid >> 6, lane = tid & 63;
    if (!lane) { red[wave] = s; red[wave + 4] = q; }
    __syncthreads();
    if (!tid) {
      partials[(b * NCH + c) * 2]     = red[0] + red[1] + red[2] + red[3];
      partials[(b * NCH + c) * 2 + 1] = red[4] + red[5] + red[6] + red[7];
    }
    return;
  }

  __shared__ float a[NAD];
  if (tid < NAD) a[tid] = alphas[tid];
  __syncthreads();

  if (bid < 800) {                       // ---- dense mixes: 25 loads in flight ----
    const int g = (bid < 400 ? bid : bid - 400) * 256 + tid;   // float4-group 0..102399
    const float4* src = (const float4*)(bid < 400 ? WdAll : WuAll) + g;
    float4 vals[NAD];
#pragma unroll
    for (int n = 0; n < NAD; ++n) vals[n] = src[(size_t)n * 102400];
    __builtin_amdgcn_sched_barrier(0);   // force all 25 loads before first FMA
    float4 acc = {0.f, 0.f, 0.f, 0.f};
#pragma unroll
    for (int n = 0; n < NAD; ++n) {
      acc.x += a[n] * vals[n].x; acc.y += a[n] * vals[n].y;
      acc.z += a[n] * vals[n].z; acc.w += a[n] * vals[n].w;
    }
    uint2 pk = { cvtpk(acc.x, acc.y), cvtpk(acc.z, acc.w) };
    if (bid < 400) {
      *(uint2*)(Wd + (size_t)g * 4) = pk;                    // Wd [512][1024] dense region
    } else {
      const int d = g / 100, bg = g - d * 100;               // Wu [1024][512]
      *(uint2*)(Wu + (size_t)d * BOTP + bg * 4) = pk;
    }
  } else if (bid < 808) {                // ---- wln / bln ----
    const int i = (bid - 800) * 256 + tid;
    const float* src = (i < DD) ? wlnAll : blnAll;
    const int j = (i < DD) ? i : (i - DD);
    float v[NAD];
#pragma unroll
    for (int n = 0; n < NAD; ++n) v[n] = src[(size_t)n * DD + j];
    __builtin_amdgcn_sched_barrier(0);
    float s = 0.f;
#pragma unroll
    for (int n = 0; n < NAD; ++n) s += a[n] * v[n];
    if (i < DD) wln[j] = s; else bln[j] = s;
  } else if (bid < 864) {                // ---- zero Wd rows 400..511 ----
    const int t = (bid - 808) * 256 + tid;
    int4 z = {0, 0, 0, 0};
    *(int4*)(Wd + 400 * 1024 + (size_t)t * 8) = z;
  } else {                               // ---- zero Wu cols 400..511 ----
    const int t = (bid - 864) * 256 + tid;
    const int row = t / 14, c8 = t - row * 14;
    int4 z = {0, 0, 0, 0};
    *(int4*)(Wu + (size_t)row * BOTP + 400 + c8 * 8) = z;
  }
}

// ---------------- kernel 2: normalize -> bf16 xn ----------------
// xn = (x - mu) * rs * wln + bln, per batch. 96 MB traffic, BW-bound.
__global__ __launch_bounds__(256) void norm_kernel(const float* __restrict__ x,
    const float* __restrict__ partials, const float* __restrict__ wln,
    const float* __restrict__ bln, unsigned short* __restrict__ xn)
{
  const int b = blockIdx.y;
  double sd = 0.0, qd = 0.0;
#pragma unroll 8
  for (int i = 0; i < NCH; ++i) {
    sd += partials[(b * NCH + i) * 2];
    qd += partials[(b * NCH + i) * 2 + 1];
  }
  const float mu  = (float)(sd * (1.0 / 2097152.0));
  const float var = (float)(qd * (1.0 / 2097152.0)) - mu * mu;
  const float rs  = rsqrtf(var + LN_EPS);

  const float4* xb = (const float4*)(x + (size_t)b * SS * DD);
  uint2* xnb = (uint2*)(xn + (size_t)b * SS * DD);
#pragma unroll
  for (int it = 0; it < 8; ++it) {
    const int idx = blockIdx.x * 2048 + it * 256 + threadIdx.x;   // float4 idx in batch
    const int dg = idx & 255;                                     // D-group (1024/4)
    const float4 v = xb[idx];
    const float4 w = *(const float4*)&wln[dg * 4];
    const float4 bb = *(const float4*)&bln[dg * 4];
    const float s1x = rs * w.x, s1y = rs * w.y, s1z = rs * w.z, s1w = rs * w.w;
    uint2 pk;
    pk.x = cvtpk((v.x - mu) * s1x + bb.x, (v.y - mu) * s1y + bb.y);
    pk.y = cvtpk((v.z - mu) * s1z + bb.z, (v.w - mu) * s1w + bb.w);
    xnb[idx] = pk;
  }
}

// ---------------- kernels 3/4: 128x128 MFMA GEMM, C = A[M,K] @ B[N,K]^T ----------------
// BK=64 (half the barriers of R1), LDS as two [128][32] sub-tiles (R1-identical banking).
// XCD-chunked bijective swizzle (grids % 8 == 0).
// RELU=true : relu -> bf16, repack through LDS -> coalesced int4 stores (to Cb)
// RELU=false: + Xres -> LDS f32 repack (2 halves) -> coalesced float4 stores (to Cf)
template <int KDIM, int NBN, bool RELU>
__global__ __launch_bounds__(256) void gemm_bt(
    const unsigned short* __restrict__ A, const unsigned short* __restrict__ Bm,
    const float* __restrict__ Xres, float* __restrict__ Cf,
    unsigned short* __restrict__ Cb, int N)
{
  __shared__ char smraw[32768];
  unsigned short* As = (unsigned short*)smraw;            // [2][128][32] bf16, 16 KB
  unsigned short* Bs = (unsigned short*)(smraw + 16384);  // [2][128][32] bf16, 16 KB

  const int tid = threadIdx.x, wave = tid >> 6, lane = tid & 63;
  const int wr = wave >> 1, wc = wave & 1;
  const int cpx = gridDim.x >> 3;
  const int bid = (blockIdx.x & 7) * cpx + (blockIdx.x >> 3);   // contiguous bids per XCD
  const int bcol = bid & (NBN - 1), brow = bid / NBN;
  const unsigned short* Ab = A + (size_t)(brow * 128) * KDIM;
  const unsigned short* Bb = Bm + (size_t)(bcol * 128) * KDIM;

  // stage a 128x64 K-tile as two [128][32] sub-tiles (linear LDS dest, remapped source)
  auto stageM = [&](unsigned short* S, const unsigned short* P, int k0) {
#pragma unroll
    for (int i = 0; i < 4; ++i) {
      const int r = (i & 1) * 64 + wave * 16 + (lane >> 2);
      const int c = (i >> 1) * 32 + (lane & 3) * 8;
      gload16(&S[i * 2048 + wave * 512], P + (size_t)r * KDIM + k0 + c);
    }
  };

  fx4 acc[4][4] = {};
#pragma unroll 1
  for (int t = 0; t < KDIM / 64; ++t) {
    stageM(As, Ab, t * 64);
    stageM(Bs, Bb, t * 64);
    __syncthreads();                 // vmcnt drained here (compiler-inserted)
#pragma unroll
    for (int kk = 0; kk < 2; ++kk) {
      bf8_t af[4], bf[4];
      const int ko = kk * 4096 + (lane >> 4) * 8;
#pragma unroll
      for (int m = 0; m < 4; ++m)
        af[m] = *(const bf8_t*)&As[ko + (wr * 64 + m * 16 + (lane & 15)) * 32];
#pragma unroll
      for (int n = 0; n < 4; ++n)
        bf[n] = *(const bf8_t*)&Bs[ko + (wc * 64 + n * 16 + (lane & 15)) * 32];
#pragma unroll
      for (int m = 0; m < 4; ++m)
#pragma unroll
        for (int n = 0; n < 4; ++n)
          acc[m][n] = __builtin_amdgcn_mfma_f32_16x16x32_bf16(af[m], bf[n], acc[m][n], 0, 0, 0);
    }
    __syncthreads();
  }

  // epilogue. C/D frag layout: col = lane&15, row = (lane>>4)*4 + j (m89-verified)
  if constexpr (RELU) {
    unsigned short* Hs = (unsigned short*)smraw;   // [128][128] bf16, 32 KB
    const int r0l = wr * 64 + ((lane >> 4) << 2);
    const int c0l = wc * 64 + (lane & 15);
#pragma unroll
    for (int m = 0; m < 4; ++m)
#pragma unroll
      for (int n = 0; n < 4; ++n)
#pragma unroll
        for (int j = 0; j < 4; ++j) {
          float v = acc[m][n][j];
          Hs[(r0l + m * 16 + j) * 128 + (c0l + n * 16)] = f2bf(v > 0.f ? v : 0.f);
        }
    __syncthreads();
    const size_t outbase = (size_t)(brow * 128) * N + (size_t)bcol * 128;
#pragma unroll
    for (int i = 0; i < 8; ++i) {
      const int idx = i * 256 + tid;
      const int row = idx >> 4, colg = idx & 15;
      *(int4*)(Cb + outbase + (size_t)row * N + colg * 8) = *(const int4*)&Hs[row * 128 + colg * 8];
    }
  } else {
    float* Fs = (float*)smraw;                     // [64][128] f32, 32 KB per half
#pragma unroll
    for (int h2 = 0; h2 < 2; ++h2) {
      if (wr == h2) {
        const int c0l = wc * 64 + (lane & 15);
        const int rj = (lane >> 4) << 2;
#pragma unroll
        for (int m = 0; m < 4; ++m)
#pragma unroll
          for (int n = 0; n < 4; ++n)
#pragma unroll
            for (int j = 0; j < 4; ++j)
              Fs[(m * 16 + rj + j) * 128 + (c0l + n * 16)] = acc[m][n][j];
      }
      __syncthreads();
      const size_t gb = (size_t)(brow * 128 + h2 * 64) * N + (size_t)bcol * 128;
#pragma unroll
      for (int i = 0; i < 8; ++i) {
        const int idx = i * 256 + tid;
        const int row = idx >> 5, cg = idx & 31;
        const float4 f = *(const float4*)&Fs[row * 128 + cg * 4];
        const float4 xr = *(const float4*)&Xres[gb + (size_t)row * N + cg * 4];
        float4 o = { f.x + xr.x, f.y + xr.y, f.z + xr.z, f.w + xr.w };
        *(float4*)&Cf[gb + (size_t)row * N + cg * 4] = o;
      }
      __syncthreads();
    }
  }
}

// ---------------- launcher ----------------
extern "C" void kernel_launch(void* const* d_in, const int* in_sizes, int n_in,
                              void* d_out, int out_size, void* d_ws, size_t ws_size,
                              hipStream_t stream)
{
  const float* x      = (const float*)d_in[0];
  const float* alphas = (const float*)d_in[1];
  const float* WdAll  = (const float*)d_in[2];
  const float* WuAll  = (const float*)d_in[3];
  const float* wlnAll = (const float*)d_in[6];
  const float* blnAll = (const float*)d_in[7];
  float* out = (float*)d_out;

  char* ws = (char*)d_ws;
  unsigned short* Wd  = (unsigned short*)ws;                  // [512][1024] bf16, 1 MB
  unsigned short* Wu  = (unsigned short*)(ws + (1u << 20));   // [1024][512] bf16, 1 MB
  float* wln          = (float*)(ws + (2u << 20));
  float* bln          = wln + DD;
  float* partials     = bln + DD;                             // 8*128*2 f32
  unsigned short* xn  = (unsigned short*)(ws + (3u << 20));   // [16384][1024] bf16, 32 MB
  unsigned short* h   = (unsigned short*)(ws + (35u << 20));  // [16384][512] bf16, 16 MB

  mixstats_kernel<<<1944, 256, 0, stream>>>(alphas, WdAll, WuAll, wlnAll, blnAll, x,
                                            Wd, Wu, wln, bln, partials);
  norm_kernel<<<dim3(256, NB), 256, 0, stream>>>(x, partials, wln, bln, xn);
  gemm_bt<1024, 4, true ><<<512,  256, 0, stream>>>(xn, Wd, nullptr, nullptr, h, BOTP);
  gemm_bt<512,  8, false><<<1024, 256, 0, stream>>>(h, Wu, x, out, nullptr, DD);
}

// Round 11
// 264.419 us; speedup vs baseline: 1.0408x; 1.0031x over previous
//
#include <hip/hip_runtime.h>
#include <stdint.h>

// ---------------- problem constants ----------------
#define NB   8      // batch
#define SS   2048   // seq
#define DD   1024   // embd
#define BOT  400    // bottleneck
#define BOTP 512    // padded bottleneck (padded weights zeroed -> h pad = relu(0) = 0)
#define NAD  25     // adapters
#define LN_EPS 1e-5f
#define NCH  128    // stats chunks per batch

typedef __attribute__((ext_vector_type(8))) short bf8_t;  // 8 bf16 (4 VGPRs)
typedef __attribute__((ext_vector_type(4))) float fx4;

__device__ __forceinline__ unsigned short f2bf(float f) {
  unsigned int u = __float_as_uint(f);
  u = (u + 0x7FFFu + ((u >> 16) & 1u)) >> 16;   // RNE bf16
  return (unsigned short)u;
}
// packed f32x2 -> bf16x2 (RNE), single instruction
__device__ __forceinline__ uint32_t cvtpk(float lo, float hi) {
  uint32_t r;
  asm("v_cvt_pk_bf16_f32 %0, %1, %2" : "=v"(r) : "v"(lo), "v"(hi));
  return r;
}

__device__ __forceinline__ void gload16(void* lds, const void* g) {
  __builtin_amdgcn_global_load_lds(
      (const __attribute__((address_space(1))) void*)(uintptr_t)g,
      (__attribute__((address_space(3))) void*)(uint32_t)(uintptr_t)lds,
      16, 0, 0);
}

// ---------------- kernel 1: fused weight-mix + LN partial stats (unchanged from R9) ----------------
__global__ __launch_bounds__(256) void mixstats_kernel(
    const float* __restrict__ alphas,
    const float* __restrict__ WdAll, const float* __restrict__ WuAll,
    const float* __restrict__ wlnAll, const float* __restrict__ blnAll,
    const float* __restrict__ x,
    unsigned short* __restrict__ Wd, unsigned short* __restrict__ Wu,
    float* __restrict__ wln, float* __restrict__ bln,
    float* __restrict__ partials)
{
  const int tid = threadIdx.x;
  const int bid = blockIdx.x;

  if (bid >= 920) {                      // ---- stats: 16 loads in flight ----
    const int g = bid - 920;
    const int b = g >> 7, c = g & 127;
    const float4* xb = (const float4*)(x + (size_t)b * SS * DD) + (size_t)c * 4096;
    float4 v[16];
#pragma unroll
    for (int i = 0; i < 16; ++i) v[i] = xb[i * 256 + tid];
    __builtin_amdgcn_sched_barrier(0);   // all 16 loads issued before any use
    float s = 0.f, q = 0.f;
#pragma unroll
    for (int i = 0; i < 16; ++i) {
      s += v[i].x + v[i].y + v[i].z + v[i].w;
      q += v[i].x * v[i].x + v[i].y * v[i].y + v[i].z * v[i].z + v[i].w * v[i].w;
    }
#pragma unroll
    for (int off = 32; off > 0; off >>= 1) { s += __shfl_down(s, off); q += __shfl_down(q, off); }
    __shared__ float red[8];
    const int wave = tid >> 6, lane = tid & 63;
    if (!lane) { red[wave] = s; red[wave + 4] = q; }
    __syncthreads();
    if (!tid) {
      partials[(b * NCH + c) * 2]     = red[0] + red[1] + red[2] + red[3];
      partials[(b * NCH + c) * 2 + 1] = red[4] + red[5] + red[6] + red[7];
    }
    return;
  }

  __shared__ float a[NAD];
  if (tid < NAD) a[tid] = alphas[tid];
  __syncthreads();

  if (bid < 800) {                       // ---- dense mixes: 25 loads in flight ----
    const int g = (bid < 400 ? bid : bid - 400) * 256 + tid;   // float4-group 0..102399
    const float4* src = (const float4*)(bid < 400 ? WdAll : WuAll) + g;
    float4 vals[NAD];
#pragma unroll
    for (int n = 0; n < NAD; ++n) vals[n] = src[(size_t)n * 102400];
    __builtin_amdgcn_sched_barrier(0);   // force all 25 loads before first FMA
    float4 acc = {0.f, 0.f, 0.f, 0.f};
#pragma unroll
    for (int n = 0; n < NAD; ++n) {
      acc.x += a[n] * vals[n].x; acc.y += a[n] * vals[n].y;
      acc.z += a[n] * vals[n].z; acc.w += a[n] * vals[n].w;
    }
    uint2 pk = { cvtpk(acc.x, acc.y), cvtpk(acc.z, acc.w) };
    if (bid < 400) {
      *(uint2*)(Wd + (size_t)g * 4) = pk;                    // Wd [512][1024] dense region
    } else {
      const int d = g / 100, bg = g - d * 100;               // Wu [1024][512]
      *(uint2*)(Wu + (size_t)d * BOTP + bg * 4) = pk;
    }
  } else if (bid < 808) {                // ---- wln / bln ----
    const int i = (bid - 800) * 256 + tid;
    const float* src = (i < DD) ? wlnAll : blnAll;
    const int j = (i < DD) ? i : (i - DD);
    float v[NAD];
#pragma unroll
    for (int n = 0; n < NAD; ++n) v[n] = src[(size_t)n * DD + j];
    __builtin_amdgcn_sched_barrier(0);
    float s = 0.f;
#pragma unroll
    for (int n = 0; n < NAD; ++n) s += a[n] * v[n];
    if (i < DD) wln[j] = s; else bln[j] = s;
  } else if (bid < 864) {                // ---- zero Wd rows 400..511 ----
    const int t = (bid - 808) * 256 + tid;
    int4 z = {0, 0, 0, 0};
    *(int4*)(Wd + 400 * 1024 + (size_t)t * 8) = z;
  } else {                               // ---- zero Wu cols 400..511 ----
    const int t = (bid - 864) * 256 + tid;
    const int row = t / 14, c8 = t - row * 14;
    int4 z = {0, 0, 0, 0};
    *(int4*)(Wu + (size_t)row * BOTP + 400 + c8 * 8) = z;
  }
}

// ---------------- kernel 2: normalize -> bf16 xn (unchanged from R9) ----------------
__global__ __launch_bounds__(256) void norm_kernel(const float* __restrict__ x,
    const float* __restrict__ partials, const float* __restrict__ wln,
    const float* __restrict__ bln, unsigned short* __restrict__ xn)
{
  const int b = blockIdx.y;
  double sd = 0.0, qd = 0.0;
#pragma unroll 8
  for (int i = 0; i < NCH; ++i) {
    sd += partials[(b * NCH + i) * 2];
    qd += partials[(b * NCH + i) * 2 + 1];
  }
  const float mu  = (float)(sd * (1.0 / 2097152.0));
  const float var = (float)(qd * (1.0 / 2097152.0)) - mu * mu;
  const float rs  = rsqrtf(var + LN_EPS);

  const float4* xb = (const float4*)(x + (size_t)b * SS * DD);
  uint2* xnb = (uint2*)(xn + (size_t)b * SS * DD);
#pragma unroll
  for (int it = 0; it < 8; ++it) {
    const int idx = blockIdx.x * 2048 + it * 256 + threadIdx.x;   // float4 idx in batch
    const int dg = idx & 255;                                     // D-group (1024/4)
    const float4 v = xb[idx];
    const float4 w = *(const float4*)&wln[dg * 4];
    const float4 bb = *(const float4*)&bln[dg * 4];
    const float s1x = rs * w.x, s1y = rs * w.y, s1z = rs * w.z, s1w = rs * w.w;
    uint2 pk;
    pk.x = cvtpk((v.x - mu) * s1x + bb.x, (v.y - mu) * s1y + bb.y);
    pk.y = cvtpk((v.z - mu) * s1z + bb.z, (v.w - mu) * s1w + bb.w);
    xnb[idx] = pk;
  }
}

// ---------------- kernels 3/4: 128x128 MFMA GEMM, C = A[M,K] @ B[N,K]^T ----------------
// R10: 3-buffer LDS ring (48 KB), prefetch distance 2, counted s_waitcnt vmcnt(4)
// immediately before a raw s_barrier (T4: never drain to 0 in the main loop).
// Correctness: each wave drains the next-tile's own 4 gload_lds before the shared
// barrier -> after barrier, all waves' loads for that tile are complete. WAR on a ring
// buffer is 2 barriers deep. Tail (last 2 iters) uses vmcnt(0).
// RELU=true : relu -> bf16, repack through LDS -> coalesced int4 stores (to Cb)
// RELU=false: + Xres -> LDS f32 repack (2 halves) -> coalesced float4 stores (to Cf)
template <int KDIM, int NBN, bool RELU>
__global__ __launch_bounds__(256) void gemm_bt(
    const unsigned short* __restrict__ A, const unsigned short* __restrict__ Bm,
    const float* __restrict__ Xres, float* __restrict__ Cf,
    unsigned short* __restrict__ Cb, int N)
{
  __shared__ char smraw[49152];          // 3 x (As 8KB + Bs 8KB)

  const int tid = threadIdx.x, wave = tid >> 6, lane = tid & 63;
  const int wr = wave >> 1, wc = wave & 1;
  const int cpx = gridDim.x >> 3;
  const int bid = (blockIdx.x & 7) * cpx + (blockIdx.x >> 3);   // contiguous bids per XCD
  const int bcol = bid & (NBN - 1), brow = bid / NBN;
  const unsigned short* Ab = A + (size_t)(brow * 128) * KDIM;
  const unsigned short* Bb = Bm + (size_t)(bcol * 128) * KDIM;

  // stage one 128x32 K-tile pair into ring buffer `buf`: 4 gload_lds per thread (2A+2B)
  auto stage = [&](int buf, int k0) {
    unsigned short* S = (unsigned short*)(smraw + buf * 16384);
#pragma unroll
    for (int i = 0; i < 2; ++i) {
      const int basee = (i * 256 + wave * 64) * 8;   // wave-uniform element base
      const int e   = basee + lane * 8;
      const int row = e >> 5, col = e & 31;
      gload16(&S[basee],        Ab + (size_t)row * KDIM + k0 + col);
      gload16(&S[4096 + basee], Bb + (size_t)row * KDIM + k0 + col);
    }
  };

  fx4 acc[4][4] = {};
  auto compute = [&](int buf) {
    const unsigned short* As = (const unsigned short*)(smraw + buf * 16384);
    const unsigned short* Bs = As + 4096;
    bf8_t af[4], bf[4];
    const int hi8 = (lane >> 4) * 8;
#pragma unroll
    for (int m = 0; m < 4; ++m)
      af[m] = *(const bf8_t*)&As[(wr * 64 + m * 16 + (lane & 15)) * 32 + hi8];
#pragma unroll
    for (int n = 0; n < 4; ++n)
      bf[n] = *(const bf8_t*)&Bs[(wc * 64 + n * 16 + (lane & 15)) * 32 + hi8];
#pragma unroll
    for (int m = 0; m < 4; ++m)
#pragma unroll
      for (int n = 0; n < 4; ++n)
        acc[m][n] = __builtin_amdgcn_mfma_f32_16x16x32_bf16(af[m], bf[n], acc[m][n], 0, 0, 0);
  };

  constexpr int NT = KDIM / 32;          // 32 (gemm1) / 16 (gemm2)

  // prologue: tiles 0 and 1 in flight; drain tile 0 (keep tile 1's 4 loads outstanding)
  stage(0, 0);
  stage(1, 32);
  asm volatile("s_waitcnt vmcnt(4)" ::: "memory");
  __builtin_amdgcn_s_barrier();
  __builtin_amdgcn_sched_barrier(0);

  int r = 0, w = 2;
#pragma unroll 1
  for (int t = 0; t < NT - 2; ++t) {
    stage(w, (t + 2) * 32);              // distance-2 prefetch (4 loads)
    compute(r);                          // ds_read + lgkmcnt (compiler) + 16 MFMA
    asm volatile("s_waitcnt vmcnt(4)" ::: "memory");   // drain tile t+1, keep t+2 in flight
    __builtin_amdgcn_s_barrier();
    __builtin_amdgcn_sched_barrier(0);
    r = (r == 2) ? 0 : r + 1;
    w = (w == 2) ? 0 : w + 1;
  }
  // t = NT-2: no more staging; fully drain the last tile's loads
  compute(r);
  asm volatile("s_waitcnt vmcnt(0)" ::: "memory");
  __builtin_amdgcn_s_barrier();
  __builtin_amdgcn_sched_barrier(0);
  r = (r == 2) ? 0 : r + 1;
  // t = NT-1
  compute(r);
  __syncthreads();                       // full drain before epilogue LDS reuse

  // epilogue. C/D frag layout: col = lane&15, row = (lane>>4)*4 + j (m89-verified)
  if constexpr (RELU) {
    unsigned short* Hs = (unsigned short*)smraw;   // [128][128] bf16, 32 KB
    const int r0l = wr * 64 + ((lane >> 4) << 2);
    const int c0l = wc * 64 + (lane & 15);
#pragma unroll
    for (int m = 0; m < 4; ++m)
#pragma unroll
      for (int n = 0; n < 4; ++n)
#pragma unroll
        for (int j = 0; j < 4; ++j) {
          float v = acc[m][n][j];
          Hs[(r0l + m * 16 + j) * 128 + (c0l + n * 16)] = f2bf(v > 0.f ? v : 0.f);
        }
    __syncthreads();
    const size_t outbase = (size_t)(brow * 128) * N + (size_t)bcol * 128;
#pragma unroll
    for (int i = 0; i < 8; ++i) {
      const int idx = i * 256 + tid;
      const int row = idx >> 4, colg = idx & 15;
      *(int4*)(Cb + outbase + (size_t)row * N + colg * 8) = *(const int4*)&Hs[row * 128 + colg * 8];
    }
  } else {
    float* Fs = (float*)smraw;                     // [64][128] f32, 32 KB per half
#pragma unroll
    for (int h2 = 0; h2 < 2; ++h2) {
      if (wr == h2) {
        const int c0l = wc * 64 + (lane & 15);
        const int rj = (lane >> 4) << 2;
#pragma unroll
        for (int m = 0; m < 4; ++m)
#pragma unroll
          for (int n = 0; n < 4; ++n)
#pragma unroll
            for (int j = 0; j < 4; ++j)
              Fs[(m * 16 + rj + j) * 128 + (c0l + n * 16)] = acc[m][n][j];
      }
      __syncthreads();
      const size_t gb = (size_t)(brow * 128 + h2 * 64) * N + (size_t)bcol * 128;
#pragma unroll
      for (int i = 0; i < 8; ++i) {
        const int idx = i * 256 + tid;
        const int row = idx >> 5, cg = idx & 31;
        const float4 f = *(const float4*)&Fs[row * 128 + cg * 4];
        const float4 xr = *(const float4*)&Xres[gb + (size_t)row * N + cg * 4];
        float4 o = { f.x + xr.x, f.y + xr.y, f.z + xr.z, f.w + xr.w };
        *(float4*)&Cf[gb + (size_t)row * N + cg * 4] = o;
      }
      __syncthreads();
    }
  }
}

// ---------------- launcher ----------------
extern "C" void kernel_launch(void* const* d_in, const int* in_sizes, int n_in,
                              void* d_out, int out_size, void* d_ws, size_t ws_size,
                              hipStream_t stream)
{
  const float* x      = (const float*)d_in[0];
  const float* alphas = (const float*)d_in[1];
  const float* WdAll  = (const float*)d_in[2];
  const float* WuAll  = (const float*)d_in[3];
  const float* wlnAll = (const float*)d_in[6];
  const float* blnAll = (const float*)d_in[7];
  float* out = (float*)d_out;

  char* ws = (char*)d_ws;
  unsigned short* Wd  = (unsigned short*)ws;                  // [512][1024] bf16, 1 MB
  unsigned short* Wu  = (unsigned short*)(ws + (1u << 20));   // [1024][512] bf16, 1 MB
  float* wln          = (float*)(ws + (2u << 20));
  float* bln          = wln + DD;
  float* partials     = bln + DD;                             // 8*128*2 f32
  unsigned short* xn  = (unsigned short*)(ws + (3u << 20));   // [16384][1024] bf16, 32 MB
  unsigned short* h   = (unsigned short*)(ws + (35u << 20));  // [16384][512] bf16, 16 MB

  mixstats_kernel<<<1944, 256, 0, stream>>>(alphas, WdAll, WuAll, wlnAll, blnAll, x,
                                            Wd, Wu, wln, bln, partials);
  norm_kernel<<<dim3(256, NB), 256, 0, stream>>>(x, partials, wln, bln, xn);
  gemm_bt<1024, 4, true ><<<512,  256, 0, stream>>>(xn, Wd, nullptr, nullptr, h, BOTP);
  gemm_bt<512,  8, false><<<1024, 256, 0, stream>>>(h, Wu, x, out, nullptr, DD);
}